// Round 2
// baseline (596.897 us; speedup 1.0000x reference)
//
#include <hip/hip_runtime.h>

// DCN layer, fused:
//   s[i]     = sum_j x_l[i,j] * w[j]
//   out[i,j] = x_0[i,j] * s[i] + b[j] + x_l[i,j]
// Shapes: x_l, x_0: [B=65536, DIM=1024] fp32; w, b: [1024] fp32; out: [B, DIM] fp32.
//
// v3: persistent pipelined waves.
//  - Round-1 post-mortem: compiler allocated 32 VGPRs -> it sank the x_0 loads
//    below the reduce, recreating the two-phase structure; perf tied round 0.
//  - Now each wave owns 16 consecutive rows. w,b are loaded ONCE into registers.
//    Rows are double-buffered (A/B) so the next row's 8 float4 loads are in
//    flight while the current row computes/reduces/stores: continuous issue,
//    no wave churn, no exposed second phase.
//  - __launch_bounds__(256,4) pins VGPR <= 128 so the A/B buffers stay in
//    registers; grid = 1024 blocks = exactly 4 blocks/CU resident.

#define DIM 1024
#define BLOCK 256
#define WAVES_PER_BLOCK 4
#define ROWS_PER_WAVE 16

__global__ __launch_bounds__(BLOCK, 4) void dcn_fused_kernel(
    const float* __restrict__ x_l,
    const float* __restrict__ x_0,
    const float* __restrict__ w,
    const float* __restrict__ b,
    float* __restrict__ out)
{
    const int wave  = threadIdx.x >> 6;
    const int lane  = threadIdx.x & 63;
    const int gwave = blockIdx.x * WAVES_PER_BLOCK + wave;
    const int c0    = lane * 4;

    // Wave-persistent operands: 4 KB each, read once per wave, live in regs.
    float4 wv[4], bv[4];
    #pragma unroll
    for (int k = 0; k < 4; ++k) wv[k] = *(const float4*)(w + k * 256 + c0);
    #pragma unroll
    for (int k = 0; k < 4; ++k) bv[k] = *(const float4*)(b + k * 256 + c0);

    const size_t base = (size_t)gwave * ROWS_PER_WAVE * DIM + (size_t)c0;
    const float* pl = x_l + base;
    const float* p0 = x_0 + base;
    float*       po = out + base;

    float4 xlA[4], x0A[4], xlB[4], x0B[4];

    // Prologue: row 0 -> A.
    #pragma unroll
    for (int k = 0; k < 4; ++k) xlA[k] = *(const float4*)(pl + k * 256);
    #pragma unroll
    for (int k = 0; k < 4; ++k) x0A[k] = *(const float4*)(p0 + k * 256);

    #pragma unroll
    for (int r = 0; r < ROWS_PER_WAVE; r += 2) {
        // Prefetch row r+1 -> B (always in-range: r+1 <= 15).
        #pragma unroll
        for (int k = 0; k < 4; ++k) xlB[k] = *(const float4*)(pl + DIM + k * 256);
        #pragma unroll
        for (int k = 0; k < 4; ++k) x0B[k] = *(const float4*)(p0 + DIM + k * 256);

        // Compute + store row r from A (hides B's load latency).
        {
            float partial = 0.0f;
            #pragma unroll
            for (int k = 0; k < 4; ++k) {
                partial = fmaf(xlA[k].x, wv[k].x, partial);
                partial = fmaf(xlA[k].y, wv[k].y, partial);
                partial = fmaf(xlA[k].z, wv[k].z, partial);
                partial = fmaf(xlA[k].w, wv[k].w, partial);
            }
            #pragma unroll
            for (int off = 1; off < 64; off <<= 1)
                partial += __shfl_xor(partial, off, 64);
            const float s = partial;
            #pragma unroll
            for (int k = 0; k < 4; ++k) {
                float4 o;
                o.x = fmaf(x0A[k].x, s, bv[k].x + xlA[k].x);
                o.y = fmaf(x0A[k].y, s, bv[k].y + xlA[k].y);
                o.z = fmaf(x0A[k].z, s, bv[k].z + xlA[k].z);
                o.w = fmaf(x0A[k].w, s, bv[k].w + xlA[k].w);
                *(float4*)(po + k * 256) = o;
            }
        }

        // Prefetch row r+2 -> A (compile-time skip on the final pair).
        if (r + 2 < ROWS_PER_WAVE) {
            #pragma unroll
            for (int k = 0; k < 4; ++k) xlA[k] = *(const float4*)(pl + 2 * DIM + k * 256);
            #pragma unroll
            for (int k = 0; k < 4; ++k) x0A[k] = *(const float4*)(p0 + 2 * DIM + k * 256);
        }

        // Compute + store row r+1 from B (hides A's load latency).
        {
            float partial = 0.0f;
            #pragma unroll
            for (int k = 0; k < 4; ++k) {
                partial = fmaf(xlB[k].x, wv[k].x, partial);
                partial = fmaf(xlB[k].y, wv[k].y, partial);
                partial = fmaf(xlB[k].z, wv[k].z, partial);
                partial = fmaf(xlB[k].w, wv[k].w, partial);
            }
            #pragma unroll
            for (int off = 1; off < 64; off <<= 1)
                partial += __shfl_xor(partial, off, 64);
            const float s = partial;
            #pragma unroll
            for (int k = 0; k < 4; ++k) {
                float4 o;
                o.x = fmaf(x0B[k].x, s, bv[k].x + xlB[k].x);
                o.y = fmaf(x0B[k].y, s, bv[k].y + xlB[k].y);
                o.z = fmaf(x0B[k].z, s, bv[k].z + xlB[k].z);
                o.w = fmaf(x0B[k].w, s, bv[k].w + xlB[k].w);
                *(float4*)(po + DIM + k * 256) = o;
            }
        }

        pl += 2 * DIM;
        p0 += 2 * DIM;
        po += 2 * DIM;
    }
}

extern "C" void kernel_launch(void* const* d_in, const int* in_sizes, int n_in,
                              void* d_out, int out_size, void* d_ws, size_t ws_size,
                              hipStream_t stream) {
    const float* x_l = (const float*)d_in[0];
    const float* x_0 = (const float*)d_in[1];
    const float* w   = (const float*)d_in[2];
    const float* b   = (const float*)d_in[3];
    float* out = (float*)d_out;

    const int B = in_sizes[0] / DIM;                         // 65536
    const int grid = B / (WAVES_PER_BLOCK * ROWS_PER_WAVE);  // 1024 blocks
    dcn_fused_kernel<<<grid, BLOCK, 0, stream>>>(x_l, x_0, w, b, out);
}

// Round 3
// 576.547 us; speedup vs baseline: 1.0353x; 1.0353x over previous
//
#include <hip/hip_runtime.h>

// DCN layer, fused:
//   s[i]     = sum_j x_l[i,j] * w[j]
//   out[i,j] = x_0[i,j] * s[i] + b[j] + x_l[i,j]
// Shapes: x_l, x_0: [B=65536, DIM=1024] fp32; w, b: [1024] fp32; out: [B, DIM] fp32.
//
// v4: explicit vmcnt pipeline via volatile asm.
//  - Rounds 1-2 post-mortem: hipcc sinks plain C++ loads below the shuffle
//    reduce every time (VGPR 32/44 vs ~110 predicted), recreating the
//    two-exposed-latency structure that pins us at ~3 TB/s.
//  - All 16 loads (w, x_l, x_0, b -> 256 B/thread) issued as asm volatile
//    global_load_dwordx4: volatile asm is never reordered or sunk.
//  - s_waitcnt vmcnt(8): oldest 8 (w, x_l) arrived -> dot product + butterfly
//    reduce runs while x_0/b are still in flight. s_waitcnt vmcnt(0) before
//    the epilogue. Each wait is followed by sched_barrier(0) (rule #18:
//    hipcc hoists register-only FMAs past inline-asm waitcnt).
//  - One row per wave, no LDS, no barrier, no launch_bounds cap.

#define DIM 1024
#define BLOCK 256   // 4 independent waves per block, 1 row per wave

typedef float f32x4 __attribute__((ext_vector_type(4)));

__global__ __launch_bounds__(BLOCK) void dcn_fused_kernel(
    const float* __restrict__ x_l,
    const float* __restrict__ x_0,
    const float* __restrict__ w,
    const float* __restrict__ b,
    float* __restrict__ out)
{
    const int wave = threadIdx.x >> 6;
    const int lane = threadIdx.x & 63;
    const int row  = blockIdx.x * 4 + wave;
    const size_t base = (size_t)row * DIM;
    const int c0 = lane * 4;                  // this lane's float4 column in chunk 0

    f32x4 wv[4], xl[4], x0[4], bv[4];

    // ---- Issue ALL 16 loads, in program order, uninterruptible by the
    //      compiler. Oldest 8 = {w, x_l} (needed first); youngest 8 =
    //      {x_0, b} (needed only after the reduce).
    #pragma unroll
    for (int k = 0; k < 4; ++k)
        asm volatile("global_load_dwordx4 %0, %1, off"
                     : "=v"(wv[k]) : "v"(w + k * 256 + c0));
    #pragma unroll
    for (int k = 0; k < 4; ++k)
        asm volatile("global_load_dwordx4 %0, %1, off"
                     : "=v"(xl[k]) : "v"(x_l + base + k * 256 + c0));
    #pragma unroll
    for (int k = 0; k < 4; ++k)
        asm volatile("global_load_dwordx4 %0, %1, off"
                     : "=v"(x0[k]) : "v"(x_0 + base + k * 256 + c0));
    #pragma unroll
    for (int k = 0; k < 4; ++k)
        asm volatile("global_load_dwordx4 %0, %1, off"
                     : "=v"(bv[k]) : "v"(b + k * 256 + c0));

    // ---- Wait for w + x_l only; x_0/b stay in flight under the reduce.
    asm volatile("s_waitcnt vmcnt(8)" ::: "memory");
    __builtin_amdgcn_sched_barrier(0);

    float partial = 0.0f;
    #pragma unroll
    for (int k = 0; k < 4; ++k) {
        partial = fmaf(xl[k].x, wv[k].x, partial);
        partial = fmaf(xl[k].y, wv[k].y, partial);
        partial = fmaf(xl[k].z, wv[k].z, partial);
        partial = fmaf(xl[k].w, wv[k].w, partial);
    }

    // Wave-64 butterfly: every lane ends with the full row sum.
    #pragma unroll
    for (int off = 1; off < 64; off <<= 1)
        partial += __shfl_xor(partial, off, 64);
    const float s = partial;

    // ---- Now require x_0 + b.
    asm volatile("s_waitcnt vmcnt(0)" ::: "memory");
    __builtin_amdgcn_sched_barrier(0);

    #pragma unroll
    for (int k = 0; k < 4; ++k) {
        float4 o;
        o.x = fmaf(x0[k].x, s, bv[k].x + xl[k].x);
        o.y = fmaf(x0[k].y, s, bv[k].y + xl[k].y);
        o.z = fmaf(x0[k].z, s, bv[k].z + xl[k].z);
        o.w = fmaf(x0[k].w, s, bv[k].w + xl[k].w);
        *(float4*)(out + base + k * 256 + c0) = o;
    }
}

extern "C" void kernel_launch(void* const* d_in, const int* in_sizes, int n_in,
                              void* d_out, int out_size, void* d_ws, size_t ws_size,
                              hipStream_t stream) {
    const float* x_l = (const float*)d_in[0];
    const float* x_0 = (const float*)d_in[1];
    const float* w   = (const float*)d_in[2];
    const float* b   = (const float*)d_in[3];
    float* out = (float*)d_out;

    const int B = in_sizes[0] / DIM;           // 65536
    dcn_fused_kernel<<<B / 4, BLOCK, 0, stream>>>(x_l, x_0, w, b, out);
}